// Round 15
// baseline (26.873 us; speedup 1.0000x reference)
//
#include <hip/hip_runtime.h>
#include <math.h>
#include <stdint.h>

#define RESO 128
#define NUM_FEAT 16
#define DATA_DIM 16
#define MLP_W 128
#define NFREQ 4
#define BATCH 1024
#define NS 442
#define NT 256
#define NWAVES 4
#define STEPF ((float)(1.3 / 128.0))

typedef __attribute__((ext_vector_type(8))) short short8;
typedef __attribute__((ext_vector_type(4))) float f32x4;
typedef __attribute__((ext_vector_type(2))) float f32x2;
typedef __attribute__((ext_vector_type(4))) int int4v;

static __device__ __forceinline__ unsigned short f2bf(float f) {
    union { float f; uint32_t u; } v; v.f = f;
    uint32_t r = v.u + 0x7FFFu + ((v.u >> 16) & 1u);   // round-nearest-even
    return (unsigned short)(r >> 16);
}
static __device__ __forceinline__ uint32_t pack2bf(float a, float b) {
    return (uint32_t)f2bf(a) | ((uint32_t)f2bf(b) << 16);
}

// ---------------- Morton ----------------
static __device__ __forceinline__ uint32_t expand_bits(uint32_t v) {
    v = (v * 65537u) & 4278190335u;
    v = (v * 257u)   & 251719695u;
    v = (v * 17u)    & 3272356035u;
    v = (v * 5u)     & 1227133513u;
    return v;
}

// ---- Main: one block (256 thr, 4 waves) per ray; 2 sample slots/thread ----
__global__ __launch_bounds__(NT) void nerf_main_kernel(
    const float* __restrict__ rays_o, const float* __restrict__ rays_d,
    const float* __restrict__ grid, const float* __restrict__ cbg,
    const float* __restrict__ W1g, const float* __restrict__ b1g,
    const float* __restrict__ W2g, const float* __restrict__ b2g,
    float* __restrict__ out_rgb, float* __restrict__ out_alpha) {

    __shared__ __align__(16) float cbs[NUM_FEAT * DATA_DIM];
    __shared__ __align__(16) float pe_b1s[MLP_W];              // b1[h] + pe . W1[16:40, h]
    __shared__ __align__(16) float W2s[MLP_W * 4];
    __shared__ __align__(16) unsigned short W1pL[8 * 64 * 8];  // packed A-fragments, 8 KB
    __shared__ float wtot[2][NWAVES];
    __shared__ float wred[NWAVES][4];

    const int b = blockIdx.x;
    const int t = threadIdx.x;
    const int wid = t >> 6;
    const int lane = t & 63;
    const int g = lane >> 4;

    // per-ray setup (broadcast loads)
    const float o0 = rays_o[b * 3 + 0], o1 = rays_o[b * 3 + 1], o2 = rays_o[b * 3 + 2];
    const float d0 = rays_d[b * 3 + 0], d1 = rays_d[b * 3 + 1], d2 = rays_d[b * 3 + 2];
    const float R = 1.3f;
    float sd0 = (fabsf(d0) < 1e-8f) ? 1e-8f : d0;
    float sd1 = (fabsf(d1) < 1e-8f) ? 1e-8f : d1;
    float sd2 = (fabsf(d2) < 1e-8f) ? 1e-8f : d2;
    float ta0 = (-R - o0) / sd0, tb0 = (R - o0) / sd0;
    float ta1 = (-R - o1) / sd1, tb1 = (R - o1) / sd1;
    float ta2 = (-R - o2) / sd2, tb2 = (R - o2) / sd2;
    float tmin = fmaxf(fmaxf(fminf(ta0, tb0), fminf(ta1, tb1)), fminf(ta2, tb2));
    float tmax = fminf(fminf(fmaxf(ta0, tb0), fmaxf(ta1, tb1)), fmaxf(ta2, tb2));
    float tnear = fmaxf(tmin, 0.0f);
    float nrm = sqrtf(d0 * d0 + d1 * d1 + d2 * d2);

    cbs[t] = cbg[t];
    W2s[t] = W2g[t];
    W2s[NT + t] = W2g[NT + t];

    // pack A-fragments of W1d^T into LDS: A[h][k]=W1[k][h] (k<16 else 0)
    for (int idx = t; idx < 8 * 64 * 8; idx += NT) {
        int j = idx & 7, l = (idx >> 3) & 63, mh = idx >> 9;
        int k = (l >> 4) * 8 + j;
        float v = (k < DATA_DIM) ? W1g[k * MLP_W + mh * 16 + (l & 15)] : 0.0f;
        W1pL[idx] = f2bf(v);
    }

    // fold positional encoding + b1 into per-ray bias (exact f32)
    if (t < MLP_W) {
        float acc = b1g[t];
#pragma unroll
        for (int f = 0; f < NFREQ; ++f) {
            float fr = (float)(1 << f);
            acc = fmaf(__sinf(d0 * fr), W1g[(DATA_DIM + f * 6 + 0) * MLP_W + t], acc);
            acc = fmaf(__sinf(d1 * fr), W1g[(DATA_DIM + f * 6 + 1) * MLP_W + t], acc);
            acc = fmaf(__sinf(d2 * fr), W1g[(DATA_DIM + f * 6 + 2) * MLP_W + t], acc);
            acc = fmaf(__cosf(d0 * fr), W1g[(DATA_DIM + f * 6 + 3) * MLP_W + t], acc);
            acc = fmaf(__cosf(d1 * fr), W1g[(DATA_DIM + f * 6 + 4) * MLP_W + t], acc);
            acc = fmaf(__cosf(d2 * fr), W1g[(DATA_DIM + f * 6 + 5) * MLP_W + t], acc);
        }
        pe_b1s[t] = acc;
    }
    __syncthreads();

    // ---- per-slot heavy path (gather + MFMA MLP), wave-skippable ----
    auto process = [&](int s, float& alpha, float& c0, float& c1, float& c2) {
        float i0 = tnear + (float)s * STEPF;
        float tm = i0 + 0.5f * STEPF;
        float delta = STEPF * nrm;
        float px = o0 + d0 * tm, py = o1 + d1 * tm, pz = o2 + d2 * tm;
        bool m = (s < NS) && (tm < tmax) &&
                 (fabsf(px) <= R) && (fabsf(py) <= R) && (fabsf(pz) <= R);
        alpha = 0.0f; c0 = 0.0f; c1 = 0.0f; c2 = 0.0f;
        if (!__any((int)m)) return;

        float x[DATA_DIM];
#pragma unroll
        for (int j = 0; j < DATA_DIM; ++j) x[j] = 0.0f;

        if (m) {
            float gx = (px / R + 1.0f) * (RESO * 0.5f);
            float gy = (py / R + 1.0f) * (RESO * 0.5f);
            float gz = (pz / R + 1.0f) * (RESO * 0.5f);
            float flx = floorf(gx), fly = floorf(gy), flz = floorf(gz);
            float ox = gx - flx, oy = gy - fly, oz = gz - flz;
            int ix = (int)flx, iy = (int)fly, iz = (int)flz;

            // explicit CSE: 6 expand_bits per sample (2 per axis), pre-shifted
            int ix0 = min(max(ix, 0), RESO - 1), ix1 = min(max(ix + 1, 0), RESO - 1);
            int iy0 = min(max(iy, 0), RESO - 1), iy1 = min(max(iy + 1, 0), RESO - 1);
            int iz0 = min(max(iz, 0), RESO - 1), iz1 = min(max(iz + 1, 0), RESO - 1);
            uint32_t ex0 = expand_bits((uint32_t)ix0), ex1 = expand_bits((uint32_t)ix1);
            uint32_t ey0 = expand_bits((uint32_t)iy0) << 1, ey1 = expand_bits((uint32_t)iy1) << 1;
            uint32_t ez0 = expand_bits((uint32_t)iz0) << 2, ez1 = expand_bits((uint32_t)iz1) << 2;
            float wx0 = 1.0f - ox, wy0 = 1.0f - oy, wz0 = 1.0f - oz;

#pragma unroll
            for (int n = 0; n < 8; ++n) {
                int bx = (n >> 2) & 1, by = (n >> 1) & 1, bz = n & 1;
                uint32_t mi = (bx ? ex1 : ex0) | (by ? ey1 : ey0) | (bz ? ez1 : ez0);
                float wv = (bx ? ox : wx0) * (by ? oy : wy0) * (bz ? oz : wz0);

                const float4* g4 = (const float4*)(grid + ((size_t)mi << 4));
                float4 A = g4[0], B = g4[1], C = g4[2], D = g4[3];
                float v[16] = {A.x, A.y, A.z, A.w, B.x, B.y, B.z, B.w,
                               C.x, C.y, C.z, C.w, D.x, D.y, D.z, D.w};

                // tournament argmax (first-max-wins), depth ~4 vs serial 15
                float w01v = fmaxf(v[0], v[1]);   int w01i = (v[1] > v[0]) ? 1 : 0;
                float w23v = fmaxf(v[2], v[3]);   int w23i = (v[3] > v[2]) ? 3 : 2;
                float w45v = fmaxf(v[4], v[5]);   int w45i = (v[5] > v[4]) ? 5 : 4;
                float w67v = fmaxf(v[6], v[7]);   int w67i = (v[7] > v[6]) ? 7 : 6;
                float w89v = fmaxf(v[8], v[9]);   int w89i = (v[9] > v[8]) ? 9 : 8;
                float wabv = fmaxf(v[10], v[11]); int wabi = (v[11] > v[10]) ? 11 : 10;
                float wcdv = fmaxf(v[12], v[13]); int wcdi = (v[13] > v[12]) ? 13 : 12;
                float wefv = fmaxf(v[14], v[15]); int wefi = (v[15] > v[14]) ? 15 : 14;
                float q0v = fmaxf(w01v, w23v);    int q0i = (w23v > w01v) ? w23i : w01i;
                float q1v = fmaxf(w45v, w67v);    int q1i = (w67v > w45v) ? w67i : w45i;
                float q2v = fmaxf(w89v, wabv);    int q2i = (wabv > w89v) ? wabi : w89i;
                float q3v = fmaxf(wcdv, wefv);    int q3i = (wefv > wcdv) ? wefi : wcdi;
                float h0v = fmaxf(q0v, q1v);      int h0i = (q1v > q0v) ? q1i : q0i;
                float h1v = fmaxf(q2v, q3v);      int h1i = (q3v > q2v) ? q3i : q2i;
                int bi = (h1v > h0v) ? h1i : h0i;

                const float4* cbr = (const float4*)&cbs[bi * DATA_DIM];
                float4 ca = cbr[0], cb4 = cbr[1], cc = cbr[2], cd = cbr[3];
                x[0]  = fmaf(wv, ca.x,  x[0]);  x[1]  = fmaf(wv, ca.y,  x[1]);
                x[2]  = fmaf(wv, ca.z,  x[2]);  x[3]  = fmaf(wv, ca.w,  x[3]);
                x[4]  = fmaf(wv, cb4.x, x[4]);  x[5]  = fmaf(wv, cb4.y, x[5]);
                x[6]  = fmaf(wv, cb4.z, x[6]);  x[7]  = fmaf(wv, cb4.w, x[7]);
                x[8]  = fmaf(wv, cc.x,  x[8]);  x[9]  = fmaf(wv, cc.y,  x[9]);
                x[10] = fmaf(wv, cc.z,  x[10]); x[11] = fmaf(wv, cc.w,  x[11]);
                x[12] = fmaf(wv, cd.x,  x[12]); x[13] = fmaf(wv, cd.y,  x[13]);
                x[14] = fmaf(wv, cd.z,  x[14]); x[15] = fmaf(wv, cd.w,  x[15]);
            }
        }

        // MFMA MLP (per-wave, transposed)
        uint32_t wp[8];
#pragma unroll
        for (int i = 0; i < 8; ++i) wp[i] = pack2bf(x[2 * i], x[2 * i + 1]);

        short8 Bf[4];
#pragma unroll
        for (int ns = 0; ns < 4; ++ns) {
            int src = ns * 16 + (lane & 15);
            int v0a = __shfl((int)wp[0], src, 64), v0b = __shfl((int)wp[4], src, 64);
            int v1a = __shfl((int)wp[1], src, 64), v1b = __shfl((int)wp[5], src, 64);
            int v2a = __shfl((int)wp[2], src, 64), v2b = __shfl((int)wp[6], src, 64);
            int v3a = __shfl((int)wp[3], src, 64), v3b = __shfl((int)wp[7], src, 64);
            union { int4v i; short8 s; } u;
            u.i.x = (g == 0) ? v0a : (g == 1) ? v0b : 0;
            u.i.y = (g == 0) ? v1a : (g == 1) ? v1b : 0;
            u.i.z = (g == 0) ? v2a : (g == 1) ? v2b : 0;
            u.i.w = (g == 0) ? v3a : (g == 1) ? v3b : 0;
            Bf[ns] = u.s;
        }

        // layer-2 partials as float2 vectors (lowers to v_pk_fma_f32)
        f32x2 p01[4], p23[4];
#pragma unroll
        for (int ns = 0; ns < 4; ++ns) {
            p01[ns] = (f32x2)(0.0f);
            p23[ns] = (f32x2)(0.0f);
        }

        const int4v* Ap = (const int4v*)W1pL;
#pragma unroll
        for (int mh = 0; mh < 8; ++mh) {
            union { int4v i; short8 s; } ua;
            ua.i = Ap[mh * 64 + lane];
            short8 Af = ua.s;

            f32x4 bias = *(const f32x4*)&pe_b1s[mh * 16 + 4 * g];
            f32x4 accv[4];
            accv[0] = __builtin_amdgcn_mfma_f32_16x16x32_bf16(Af, Bf[0], bias, 0, 0, 0);
            accv[1] = __builtin_amdgcn_mfma_f32_16x16x32_bf16(Af, Bf[1], bias, 0, 0, 0);
            accv[2] = __builtin_amdgcn_mfma_f32_16x16x32_bf16(Af, Bf[2], bias, 0, 0, 0);
            accv[3] = __builtin_amdgcn_mfma_f32_16x16x32_bf16(Af, Bf[3], bias, 0, 0, 0);

            f32x2 w01[4], w23[4];
#pragma unroll
            for (int r = 0; r < 4; ++r) {
                float4 wr = *(const float4*)&W2s[(mh * 16 + 4 * g + r) * 4];  // LDS
                w01[r].x = wr.x; w01[r].y = wr.y;
                w23[r].x = wr.z; w23[r].y = wr.w;
            }
#pragma unroll
            for (int ns = 0; ns < 4; ++ns) {
#pragma unroll
                for (int r = 0; r < 4; ++r) {
                    float h = fmaxf(accv[ns][r], 0.0f);
                    f32x2 h2; h2.x = h; h2.y = h;
                    p01[ns] = h2 * w01[r] + p01[ns];   // v_pk_fma_f32
                    p23[ns] = h2 * w23[r] + p23[ns];
                }
            }
        }

        // butterfly over lane bits 4,5 (groups hold disjoint h-row sets)
#pragma unroll
        for (int ns = 0; ns < 4; ++ns) {
            float a = p01[ns].x, bb = p01[ns].y, cC = p23[ns].x, dd = p23[ns].y;
            a  += __shfl_xor(a, 16, 64);  a  += __shfl_xor(a, 32, 64);
            bb += __shfl_xor(bb, 16, 64); bb += __shfl_xor(bb, 32, 64);
            cC += __shfl_xor(cC, 16, 64); cC += __shfl_xor(cC, 32, 64);
            dd += __shfl_xor(dd, 16, 64); dd += __shfl_xor(dd, 32, 64);
            p01[ns].x = a; p01[ns].y = bb; p23[ns].x = cC; p23[ns].y = dd;
        }

        float pre0 = (g == 0) ? p01[0].x : (g == 1) ? p01[1].x : (g == 2) ? p01[2].x : p01[3].x;
        float pre1 = (g == 0) ? p01[0].y : (g == 1) ? p01[1].y : (g == 2) ? p01[2].y : p01[3].y;
        float pre2 = (g == 0) ? p23[0].x : (g == 1) ? p23[1].x : (g == 2) ? p23[2].x : p23[3].x;
        float pre3 = (g == 0) ? p23[0].y : (g == 1) ? p23[1].y : (g == 2) ? p23[2].y : p23[3].y;
        pre0 += b2g[0]; pre1 += b2g[1]; pre2 += b2g[2]; pre3 += b2g[3];

        if (m) {
            float dens = fmaxf(pre0, 0.0f);
            alpha = 1.0f - __expf(-dens * delta);
            c0 = 1.0f / (1.0f + __expf(-pre1));
            c1 = 1.0f / (1.0f + __expf(-pre2));
            c2 = 1.0f / (1.0f + __expf(-pre3));
        }
    };

    float alphaA, c0A, c1A, c2A, alphaB, c0B, c1B, c2B;
    process(t, alphaA, c0A, c1A, c2A);            // samples 0..255
    process(NT + t, alphaB, c0B, c1B, c2B);       // samples 256..511 (mostly skipped)

    // ---- compositing: two chained chunks, wave scans + cross-wave combine ----
    float incA = 1.0f - alphaA + 1e-10f;
    float incB = 1.0f - alphaB + 1e-10f;
#pragma unroll
    for (int off = 1; off < 64; off <<= 1) {
        float uA = __shfl_up(incA, off, 64);
        float uB = __shfl_up(incB, off, 64);
        if (lane >= off) { incA *= uA; incB *= uB; }
    }
    float exclA = __shfl_up(incA, 1, 64);
    float exclB = __shfl_up(incB, 1, 64);
    if (lane == 0) { exclA = 1.0f; exclB = 1.0f; }
    if (lane == 63) { wtot[0][wid] = incA; wtot[1][wid] = incB; }
    __syncthreads();

    float wpreA = 1.0f;
#pragma unroll
    for (int w = 0; w < NWAVES; ++w)
        if (w < wid) wpreA *= wtot[0][w];
    float PA = wtot[0][0] * wtot[0][1] * wtot[0][2] * wtot[0][3];
    float wpreB = PA;
#pragma unroll
    for (int w = 0; w < NWAVES; ++w)
        if (w < wid) wpreB *= wtot[1][w];

    float wgtA = alphaA * wpreA * exclA;
    float wgtB = alphaB * wpreB * exclB;
    float r0 = wgtA * c0A + wgtB * c0B;
    float r1 = wgtA * c1A + wgtB * c1B;
    float r2 = wgtA * c2A + wgtB * c2B;
    float rw = wgtA + wgtB;

    out_alpha[b * NS + t] = alphaA;
    if (t < NS - NT) out_alpha[b * NS + NT + t] = alphaB;

    // ---- final rgb reduction ----
#pragma unroll
    for (int off = 32; off >= 1; off >>= 1) {
        r0 += __shfl_down(r0, off, 64);
        r1 += __shfl_down(r1, off, 64);
        r2 += __shfl_down(r2, off, 64);
        rw += __shfl_down(rw, off, 64);
    }
    if (lane == 0) { wred[wid][0] = r0; wred[wid][1] = r1; wred[wid][2] = r2; wred[wid][3] = rw; }
    __syncthreads();
    if (t == 0) {
        float s0 = 0, s1 = 0, s2 = 0, sw = 0;
#pragma unroll
        for (int i = 0; i < NWAVES; ++i) {
            s0 += wred[i][0]; s1 += wred[i][1]; s2 += wred[i][2]; sw += wred[i][3];
        }
        float bg = 1.0f - sw;
        out_rgb[b * 3 + 0] = s0 + bg;
        out_rgb[b * 3 + 1] = s1 + bg;
        out_rgb[b * 3 + 2] = s2 + bg;
    }
}

extern "C" void kernel_launch(void* const* d_in, const int* in_sizes, int n_in,
                              void* d_out, int out_size, void* d_ws, size_t ws_size,
                              hipStream_t stream) {
    const float* rays_o   = (const float*)d_in[0];
    const float* rays_d   = (const float*)d_in[1];
    const float* grid     = (const float*)d_in[2];
    const float* codebook = (const float*)d_in[3];
    const float* W1       = (const float*)d_in[4];
    const float* b1       = (const float*)d_in[5];
    const float* W2       = (const float*)d_in[6];
    const float* b2       = (const float*)d_in[7];
    float* out = (float*)d_out;

    nerf_main_kernel<<<BATCH, NT, 0, stream>>>(
        rays_o, rays_d, grid, codebook, W1, b1, W2, b2,
        out /* rgb: 1024*3 */, out + BATCH * 3 /* alpha: 1024*442 */);
}